// Round 4
// baseline (266.195 us; speedup 1.0000x reference)
//
#include <hip/hip_runtime.h>
#include <hip/hip_bf16.h>

#define NREV 500000
#define DIM  128
#define KDIM 384

typedef __attribute__((ext_vector_type(4))) float f32x4;
typedef __attribute__((ext_vector_type(8))) short bf16x8;

__device__ __forceinline__ unsigned short f2bf_s(float x) {
    // round-to-nearest-even f32 -> bf16
    unsigned int u = __builtin_bit_cast(unsigned int, x);
    u = (u + 0x7FFFu + ((u >> 16) & 1u)) >> 16;
    return (unsigned short)u;
}

// W [384][128] f32 -> Bw frag-linear bf16:
// Bw[((ks*8+fg)*64 + l)*8 + j] = bf16( W[ks*32 + (l>>4)*8 + j][fg*16 + (l&15)] )
// so each lane's 16B B-fragment is one contiguous dwordx4 from L2.
__global__ void wconv_kernel(const float* __restrict__ W,
                             unsigned short* __restrict__ Bw) {
    int e = blockIdx.x * 256 + threadIdx.x;
    if (e < 12 * 8 * 64 * 8) {
        int j  = e & 7;
        int l  = (e >> 3) & 63;
        int fg = (e >> 9) & 7;
        int ks = e >> 12;
        int n = fg * 16 + (l & 15);
        int k = ks * 32 + ((l >> 4) << 3) + j;
        Bw[e] = f2bf_s(W[k * DIM + n]);
    }
}

// pack hi16 of two f32 into one dword of two bf16 (truncation; error budget ok,
// measured absmax 0.031 vs threshold 0.109): single v_perm_b32
__device__ __forceinline__ unsigned int pk2(float lo, float hi) {
    return __builtin_amdgcn_perm(__builtin_bit_cast(unsigned int, hi),
                                 __builtin_bit_cast(unsigned int, lo),
                                 0x07060302u);
}
__device__ __forceinline__ bf16x8 cvt8(f32x4 a, f32x4 b) {
    union { bf16x8 v; unsigned int u[4]; } U;
    U.u[0] = pk2(a[0], a[1]);
    U.u[1] = pk2(a[2], a[3]);
    U.u[2] = pk2(b[0], b[1]);
    U.u[3] = pk2(b[2], b[3]);
    return U.v;
}

// Fused gather + GEMM + ReLU. ZERO LDS, ZERO barriers.
// Block: 128 rows x 128 cols, 4 waves, each 64x64 (wr=row half, wc=col half).
// Each wave gathers its own A fragments register-direct (wc-pair duplication
// absorbed by L1/L2); B fragments register-direct from L2-resident Bw.
// Fully-unrolled 12-step K-loop = one basic block -> compiler software-
// pipelines the gather loads across steps with no forced vmcnt(0) drains.
__global__ __launch_bounds__(256, 2) void agg_kernel(
    const float* __restrict__ rev,
    const float* __restrict__ item,
    const float* __restrict__ user,
    const int*   __restrict__ uidx,
    const int*   __restrict__ iidx,
    const unsigned short* __restrict__ Bw,
    float* __restrict__ out)
{
    const int t    = threadIdx.x;
    const int wid  = t >> 6, lane = t & 63;
    const int wr   = wid >> 1, wc = wid & 1;
    const int lm   = lane & 15, lk = lane >> 4;
    const int r0   = blockIdx.x * 128;

    // Per-lane A base pointers: 3 tables x 4 mf fragments, + lk*8 f32.
    // A-frag for MFMA 16x16x32: lane (lm,lk) holds row base+lm,
    // k = kk*32 + lk*8 .. +8; per K-step the byte offset is an immediate.
    const float* baseA[3][4];
    #pragma unroll
    for (int mf = 0; mf < 4; ++mf) {
        int r = r0 + wr * 64 + mf * 16 + lm;
        if (r >= NREV) r = NREV - 1;            // clamp tail; stores predicated
        baseA[0][mf] = rev  + (size_t)r * DIM + lk * 8;
        baseA[1][mf] = user + (size_t)uidx[r] * DIM + lk * 8;
        baseA[2][mf] = item + (size_t)iidx[r] * DIM + lk * 8;
    }

    f32x4 acc[4][4];
    #pragma unroll
    for (int i = 0; i < 4; ++i)
        #pragma unroll
        for (int j = 0; j < 4; ++j)
            acc[i][j] = (f32x4){0.f, 0.f, 0.f, 0.f};

    const unsigned short* bbase = Bw + ((wc * 4) * 64 + lane) * 8;

    #pragma unroll
    for (int s = 0; s < 12; ++s) {
        // ---- A loads: 8 x dwordx4, offsets are compile-time immediates
        f32x4 a0[4], a1[4];
        #pragma unroll
        for (int mf = 0; mf < 4; ++mf) {
            const float* p = baseA[s >> 2][mf] + (s & 3) * 32;
            a0[mf] = *reinterpret_cast<const f32x4*>(p);
            a1[mf] = *reinterpret_cast<const f32x4*>(p + 4);
        }
        // ---- B loads: 4 x dwordx4 from L2-resident frag-linear Bw
        bf16x8 bfrag[4];
        #pragma unroll
        for (int nf = 0; nf < 4; ++nf)
            bfrag[nf] = *reinterpret_cast<const bf16x8*>(
                bbase + (size_t)(s * 8 + nf) * 64 * 8);

        // ---- convert + MFMA
        __builtin_amdgcn_s_setprio(1);
        #pragma unroll
        for (int mf = 0; mf < 4; ++mf) {
            bf16x8 af = cvt8(a0[mf], a1[mf]);
            #pragma unroll
            for (int nf = 0; nf < 4; ++nf)
                acc[mf][nf] = __builtin_amdgcn_mfma_f32_16x16x32_bf16(
                    af, bfrag[nf], acc[mf][nf], 0, 0, 0);
        }
        __builtin_amdgcn_s_setprio(0);
    }

    // ---- epilogue: ReLU + f32 store (C/D: col=lane&15, row=(lane>>4)*4+j)
    #pragma unroll
    for (int mf = 0; mf < 4; ++mf) {
        #pragma unroll
        for (int j = 0; j < 4; ++j) {
            int row = r0 + wr * 64 + mf * 16 + lk * 4 + j;
            if (row < NREV) {
                float* orow = out + (size_t)row * DIM + wc * 64;
                #pragma unroll
                for (int nf = 0; nf < 4; ++nf)
                    orow[nf * 16 + lm] = fmaxf(acc[mf][nf][j], 0.0f);
            }
        }
    }
}

extern "C" void kernel_launch(void* const* d_in, const int* in_sizes, int n_in,
                              void* d_out, int out_size, void* d_ws, size_t ws_size,
                              hipStream_t stream) {
    const float* rev  = (const float*)d_in[0];
    const float* item = (const float*)d_in[1];
    const float* user = (const float*)d_in[2];
    const int*   uidx = (const int*)d_in[3];
    const int*   iidx = (const int*)d_in[4];
    const float* W    = (const float*)d_in[5];
    unsigned short* Bw = (unsigned short*)d_ws;   // 12*8*64*8*2 = 98304 B
    float* out = (float*)d_out;

    wconv_kernel<<<192, 256, 0, stream>>>(W, Bw);

    int nblocks = (NREV + 127) / 128;   // 3907
    agg_kernel<<<nblocks, 256, 0, stream>>>(rev, item, user, uidx, iidx, Bw, out);
}

// Round 5
// 182.373 us; speedup vs baseline: 1.4596x; 1.4596x over previous
//
#include <hip/hip_runtime.h>
#include <hip/hip_bf16.h>

#define NREV 500000
#define DIM  128
#define KDIM 384

typedef __attribute__((ext_vector_type(4))) float f32x4;
typedef __attribute__((ext_vector_type(8))) short bf16x8;

__device__ __forceinline__ unsigned short f2bf_s(float x) {
    // round-to-nearest-even f32 -> bf16
    unsigned int u = __builtin_bit_cast(unsigned int, x);
    u = (u + 0x7FFFu + ((u >> 16) & 1u)) >> 16;
    return (unsigned short)u;
}

// W [384][128] f32 -> Bw frag-linear bf16:
// Bw[((ks*8+fg)*64 + l)*8 + j] = bf16( W[ks*32 + (l>>4)*8 + j][fg*16 + (l&15)] )
// so each lane's 16B B-fragment is one contiguous dwordx4 (L2-resident, 96KB).
__global__ void wconv_kernel(const float* __restrict__ W,
                             unsigned short* __restrict__ Bw) {
    int e = blockIdx.x * 256 + threadIdx.x;
    if (e < 12 * 8 * 64 * 8) {
        int j  = e & 7;
        int l  = (e >> 3) & 63;
        int fg = (e >> 9) & 7;
        int ks = e >> 12;
        int n = fg * 16 + (l & 15);
        int k = ks * 32 + ((l >> 4) << 3) + j;
        Bw[e] = f2bf_s(W[k * DIM + n]);
    }
}

__device__ __forceinline__ void gload_lds16(const void* g, void* l) {
    __builtin_amdgcn_global_load_lds(
        (const __attribute__((address_space(1))) void*)g,
        (__attribute__((address_space(3))) void*)l, 16, 0, 0);
}

// pack hi16 of two f32 into one dword of two bf16 (truncation; absmax 0.031
// vs threshold 0.109): single v_perm_b32
__device__ __forceinline__ unsigned int pk2(float lo, float hi) {
    return __builtin_amdgcn_perm(__builtin_bit_cast(unsigned int, hi),
                                 __builtin_bit_cast(unsigned int, lo),
                                 0x07060302u);
}
__device__ __forceinline__ bf16x8 cvt8(f32x4 a, f32x4 b) {
    union { bf16x8 v; unsigned int u[4]; } U;
    U.u[0] = pk2(a[0], a[1]);
    U.u[1] = pk2(a[2], a[3]);
    U.u[2] = pk2(b[0], b[1]);
    U.u[3] = pk2(b[2], b[3]);
    return U.v;
}

// Fused gather + GEMM + ReLU.
// Block: 128 rows x 128 cols, 4 waves (64x64 each). K=384 in 12 steps of 32.
// Steps 0-3: review, 4-7: user gather, 8-11: item gather.
// A: triple-buffered LDS via global_load_lds, 2-step-ahead prefetch.
// B: register-direct from L2-resident Bw, also 2-step-ahead.
// Counted vmcnt(8) retires exactly {A(s),B(s)}; {A(s+1),B(s+1)} stay in
// flight across the raw s_barrier (never drained mid-loop).
__global__ __launch_bounds__(256, 3) void agg_kernel(
    const float* __restrict__ rev,
    const float* __restrict__ item,
    const float* __restrict__ user,
    const int*   __restrict__ uidx,
    const int*   __restrict__ iidx,
    const unsigned short* __restrict__ Bw,
    float* __restrict__ out)
{
    // A: f32 [128][32] per buffer, XOR-swizzled via pre-swizzled SOURCE cols
    // (global_load_lds dest must stay linear). 3 x 16KB = 48KB -> 3 blocks/CU.
    __shared__ __align__(16) float Atile[3][128 * 32];

    const int r0   = blockIdx.x * 128;
    const int t    = threadIdx.x;
    const int wid  = t >> 6, lane = t & 63;
    const int wr   = wid >> 1, wc = wid & 1;
    const int lm   = lane & 15, lk = lane >> 4;

    // staging geometry: thread t stages row it*32+(t>>3), f32 cols (t&7)*4,
    // source col pre-swizzled so LDS byte x of row r holds col (x ^ ((r&7)<<4))
    const int srow = t >> 3;
    const int cswz = ((t & 7) ^ ((t >> 3) & 7)) << 2;

    const float* pr[4]; const float* pu[4]; const float* pi[4];
    #pragma unroll
    for (int it = 0; it < 4; ++it) {
        int gr = r0 + it * 32 + srow;
        if (gr >= NREV) gr = NREV - 1;        // clamp tail; stores predicated
        pr[it] = rev  + (size_t)gr * DIM + cswz;
        pu[it] = user + (size_t)uidx[gr] * DIM + cswz;
        pi[it] = item + (size_t)iidx[gr] * DIM + cswz;
    }

    f32x4 acc[4][4];
    #pragma unroll
    for (int i = 0; i < 4; ++i)
        #pragma unroll
        for (int j = 0; j < 4; ++j)
            acc[i][j] = (f32x4){0.f, 0.f, 0.f, 0.f};

    const int axor  = (lm & 7) << 4;
    const int koff0 = (lk * 32) ^ axor;
    const unsigned short* bbase = Bw + ((wc * 4) * 64 + lane) * 8;

    // issue 4 A-loads for step s into buffer buf (vmcnt += 4)
    auto prefetchA = [&](int s, int buf) {
        const int cb = (s & 3) * 32;
        #pragma unroll
        for (int it = 0; it < 4; ++it) {
            const float* src = ((s < 4) ? pr[it] : (s < 8) ? pu[it] : pi[it]) + cb;
            gload_lds16(src, (char*)&Atile[buf][0] + it * 4096 + t * 16);
        }
    };
    // issue 4 B-fragment register loads for step s (vmcnt += 4)
    bf16x8 breg[3][4];
    auto loadB = [&](int s, bf16x8* dst) {
        #pragma unroll
        for (int nf = 0; nf < 4; ++nf)
            dst[nf] = *reinterpret_cast<const bf16x8*>(
                bbase + (size_t)(s * 8 + nf) * 512);
    };

    auto step = [&](int s) {
        const char* la = (const char*)&Atile[s % 3][0];
        const bf16x8* bf = breg[s % 3];
        #pragma unroll
        for (int mf = 0; mf < 4; ++mf) {
            int rb = (wr * 64 + mf * 16 + lm) * 128;
            f32x4 f0 = *reinterpret_cast<const f32x4*>(la + rb + koff0);
            f32x4 f1 = *reinterpret_cast<const f32x4*>(la + rb + (koff0 ^ 16));
            bf16x8 af = cvt8(f0, f1);
            #pragma unroll
            for (int nf = 0; nf < 4; ++nf)
                acc[mf][nf] = __builtin_amdgcn_mfma_f32_16x16x32_bf16(
                    af, bf[nf], acc[mf][nf], 0, 0, 0);
        }
    };

    // prologue: {A0,B0,A1,B1} -> 16 loads outstanding
    prefetchA(0, 0); loadB(0, breg[0]);
    prefetchA(1, 1); loadB(1, breg[1]);

    #pragma unroll
    for (int s = 0; s < 12; ++s) {
        // retire {A(s),B(s)} (oldest 8); keep {A(s+1),B(s+1)} in flight
        if (s == 11) { asm volatile("s_waitcnt vmcnt(0)" ::: "memory"); }
        else         { asm volatile("s_waitcnt vmcnt(8)" ::: "memory"); }
        __builtin_amdgcn_s_barrier();   // tile-s data landed for all waves;
                                        // buffer (s+2)%3 no longer being read
        asm volatile("" ::: "memory");
        if (s < 10) {
            prefetchA(s + 2, (s + 2) % 3);
            loadB(s + 2, breg[(s + 2) % 3]);
        }
        step(s);
    }

    // epilogue: ReLU + f32 store (C/D: col=lane&15, row=(lane>>4)*4+j)
    #pragma unroll
    for (int mf = 0; mf < 4; ++mf) {
        #pragma unroll
        for (int j = 0; j < 4; ++j) {
            int row = r0 + wr * 64 + mf * 16 + lk * 4 + j;
            if (row < NREV) {
                float* orow = out + (size_t)row * DIM + wc * 64;
                #pragma unroll
                for (int nf = 0; nf < 4; ++nf)
                    orow[nf * 16 + lm] = fmaxf(acc[mf][nf][j], 0.0f);
            }
        }
    }
}

extern "C" void kernel_launch(void* const* d_in, const int* in_sizes, int n_in,
                              void* d_out, int out_size, void* d_ws, size_t ws_size,
                              hipStream_t stream) {
    const float* rev  = (const float*)d_in[0];
    const float* item = (const float*)d_in[1];
    const float* user = (const float*)d_in[2];
    const int*   uidx = (const int*)d_in[3];
    const int*   iidx = (const int*)d_in[4];
    const float* W    = (const float*)d_in[5];
    unsigned short* Bw = (unsigned short*)d_ws;   // 12*8*64*8*2 = 98304 B
    float* out = (float*)d_out;

    wconv_kernel<<<192, 256, 0, stream>>>(W, Bw);

    int nblocks = (NREV + 127) / 128;   // 3907
    agg_kernel<<<nblocks, 256, 0, stream>>>(rev, item, user, uidx, iidx, Bw, out);
}